// Round 3
// baseline (986.809 us; speedup 1.0000x reference)
//
#include <hip/hip_runtime.h>

#define HD 64
#define KP 16            // timesteps per phase (one workgroup barrier per phase)
#define NS 32            // ring slots = 2 phases (double buffer)
#define L2E 1.4426950408889634f

typedef _Float16 v2h __attribute__((ext_vector_type(2)));
typedef _Float16 h8  __attribute__((ext_vector_type(8)));

__device__ __forceinline__ float fexp2(float x) { return __builtin_amdgcn_exp2f(x); }
__device__ __forceinline__ float frcp(float x)  { return __builtin_amdgcn_rcpf(x); }
__device__ __forceinline__ float ftanh_fast(float x) {
    return 1.f - 2.f * frcp(fexp2(2.f * L2E * x) + 1.f);
}
__device__ __forceinline__ float fsig(float x) {
    return frcp(fexp2(-L2E * x) + 1.f);
}

#if __has_builtin(__builtin_amdgcn_fdot2)
__device__ __forceinline__ float FDOT2(v2h a, v2h b, float c) {
    return __builtin_amdgcn_fdot2(a, b, c, false);
}
#else
__device__ __forceinline__ float FDOT2(v2h a, v2h b, float c) {
    return fmaf((float)a.x, (float)b.x, fmaf((float)a.y, (float)b.y, c));
}
#endif

// ---- Named-scalar weight storage -------------------------------------------
// R1/R2 post-mortem: v2h wg[32] arrays are runtime-indexed at SROA time (SROA
// runs BEFORE loop unrolling), so they were demoted to scratch; the
// __syncthreads() between the init stores and in-loop loads blocks
// store-to-load forwarding from recovering them (VGPR_Count=104 < the 128
// VGPRs of weights alone -> per-step scratch reloads = the 2x gap vs the
// issue-rate model). Named scalars are SSA values from the front end: nothing
// for SROA to miss, nothing for the barrier to fence.

#define DECL32(P) \
    v2h P##_0,P##_1,P##_2,P##_3,P##_4,P##_5,P##_6,P##_7, \
        P##_8,P##_9,P##_10,P##_11,P##_12,P##_13,P##_14,P##_15, \
        P##_16,P##_17,P##_18,P##_19,P##_20,P##_21,P##_22,P##_23, \
        P##_24,P##_25,P##_26,P##_27,P##_28,P##_29,P##_30,P##_31

#define CVT2(v) v2h{(_Float16)v.x, (_Float16)v.y}
#define CVT2H(v) v2h{(_Float16)v.z, (_Float16)v.w}

// Load one 64-wide f32 weight row -> 32 named packed-f16 pairs.
#define LOAD32(W, r, P) do { \
    const float4* wp_ = (const float4*)((W) + (size_t)(r) * HD); \
    float4 v_; \
    v_=wp_[0];  P##_0 =CVT2(v_); P##_1 =CVT2H(v_); \
    v_=wp_[1];  P##_2 =CVT2(v_); P##_3 =CVT2H(v_); \
    v_=wp_[2];  P##_4 =CVT2(v_); P##_5 =CVT2H(v_); \
    v_=wp_[3];  P##_6 =CVT2(v_); P##_7 =CVT2H(v_); \
    v_=wp_[4];  P##_8 =CVT2(v_); P##_9 =CVT2H(v_); \
    v_=wp_[5];  P##_10=CVT2(v_); P##_11=CVT2H(v_); \
    v_=wp_[6];  P##_12=CVT2(v_); P##_13=CVT2H(v_); \
    v_=wp_[7];  P##_14=CVT2(v_); P##_15=CVT2H(v_); \
    v_=wp_[8];  P##_16=CVT2(v_); P##_17=CVT2H(v_); \
    v_=wp_[9];  P##_18=CVT2(v_); P##_19=CVT2H(v_); \
    v_=wp_[10]; P##_20=CVT2(v_); P##_21=CVT2H(v_); \
    v_=wp_[11]; P##_22=CVT2(v_); P##_23=CVT2H(v_); \
    v_=wp_[12]; P##_24=CVT2(v_); P##_25=CVT2H(v_); \
    v_=wp_[13]; P##_26=CVT2(v_); P##_27=CVT2H(v_); \
    v_=wp_[14]; P##_28=CVT2(v_); P##_29=CVT2H(v_); \
    v_=wp_[15]; P##_30=CVT2(v_); P##_31=CVT2H(v_); \
} while (0)

// One 8-element chunk of a 64-dot for one gate row (2 accumulator chains).
#define DOTG(P, i0, i1, i2, i3, A0, A1) \
    A0 = FDOT2(P##_##i0, p0_, A0); A1 = FDOT2(P##_##i1, p1_, A1); \
    A0 = FDOT2(P##_##i2, p2_, A0); A1 = FDOT2(P##_##i3, p3_, A1);

// 4-gate chunk: 16 v_dot2_f32_f16 on one h8 load.
#define DOTBLK4(HP, q, i0, i1, i2, i3) \
    { h8 hv_ = (HP)[q]; \
      v2h p0_={hv_[0],hv_[1]}, p1_={hv_[2],hv_[3]}; \
      v2h p2_={hv_[4],hv_[5]}, p3_={hv_[6],hv_[7]}; \
      DOTG(wgA, i0,i1,i2,i3, a00,a01) DOTG(wgB, i0,i1,i2,i3, a10,a11) \
      DOTG(wgC, i0,i1,i2,i3, a20,a21) DOTG(wgD, i0,i1,i2,i3, a30,a31) }

#define DOT4N(HP) \
    DOTBLK4(HP,0, 0,1,2,3)     DOTBLK4(HP,1, 4,5,6,7) \
    DOTBLK4(HP,2, 8,9,10,11)   DOTBLK4(HP,3, 12,13,14,15) \
    DOTBLK4(HP,4, 16,17,18,19) DOTBLK4(HP,5, 20,21,22,23) \
    DOTBLK4(HP,6, 24,25,26,27) DOTBLK4(HP,7, 28,29,30,31)

// 2-gate chunk (xproj waves).
#define DOTBLK2(HP, q, i0, i1, i2, i3) \
    { h8 hv_ = (HP)[q]; \
      v2h p0_={hv_[0],hv_[1]}, p1_={hv_[2],hv_[3]}; \
      v2h p2_={hv_[4],hv_[5]}, p3_={hv_[6],hv_[7]}; \
      DOTG(wgA, i0,i1,i2,i3, a00,a01) DOTG(wgB, i0,i1,i2,i3, a10,a11) }

#define DOT2N(HP) \
    DOTBLK2(HP,0, 0,1,2,3)     DOTBLK2(HP,1, 4,5,6,7) \
    DOTBLK2(HP,2, 8,9,10,11)   DOTBLK2(HP,3, 12,13,14,15) \
    DOTBLK2(HP,4, 16,17,18,19) DOTBLK2(HP,5, 20,21,22,23) \
    DOTBLK2(HP,6, 24,25,26,27) DOTBLK2(HP,7, 28,29,30,31)

// Wave-local recurrence pipeline, one block per batch element, 5 waves:
//   w0 (A): layer-0 recurrence (lane = hidden unit, all 4 gates in-lane).
//   w1 (C): layer-1 recurrence, same layout; also stores f32 h for the head.
//   w2/w3 (B): layer-1 input projection (2 gate rows per lane each), lag 1 phase.
//   w4 (D): output head, lag 3 phases.
// Workgroup barrier once per KP=16 steps; rings double-buffered by phase.
__launch_bounds__(320, 1)
__global__ void lstm2_kernel(const float* __restrict__ x,     // [B,T]
                             const float* __restrict__ h0in,  // [2,B,HD]
                             const float* __restrict__ c0in,  // [2,B,HD]
                             const float* __restrict__ Wih0,  // [4H,1]
                             const float* __restrict__ Whh0,  // [4H,HD]
                             const float* __restrict__ bih0,
                             const float* __restrict__ bhh0,
                             const float* __restrict__ Wih1,  // [4H,HD]
                             const float* __restrict__ Whh1,  // [4H,HD]
                             const float* __restrict__ bih1,
                             const float* __restrict__ bhh1,
                             const float* __restrict__ Wlin,  // [1,HD]
                             const float* __restrict__ blin,  // [1]
                             float* __restrict__ out,         // [B,T]
                             int B, int T)
{
    const int b    = blockIdx.x;
    const int tid  = threadIdx.x;
    const int wave = tid >> 6;
    const int lane = tid & 63;

    __shared__ __align__(16) _Float16 h0ring[NS][HD];        // layer-0 h (f16)
    __shared__ __align__(16) _Float16 h1ring[NS][HD];        // layer-1 h (f16)
    __shared__ __align__(16) float    h1f32[NS][HD + 4];     // layer-1 h (f32, head; +4 pad)
    __shared__ __align__(16) float    xpring[NS][4][HD];     // layer-1 xproj (f32)

    // ---- zero-init ALL LDS (launch-history independence), then barrier ----
    {
        _Float16* z0 = &h0ring[0][0];
        for (int i = tid; i < NS * HD; i += 320) z0[i] = (_Float16)0.f;
        _Float16* z1 = &h1ring[0][0];
        for (int i = tid; i < NS * HD; i += 320) z1[i] = (_Float16)0.f;
        float* z2 = &h1f32[0][0];
        for (int i = tid; i < NS * (HD + 4); i += 320) z2[i] = 0.f;
        float* z3 = &xpring[0][0][0];
        for (int i = tid; i < NS * 4 * HD; i += 320) z3[i] = 0.f;
    }
    __syncthreads();

    const int nphase = (T + KP - 1) / KP + 3;

    if (wave == 0) {
        // ================= A: layer-0 recurrence =================
        DECL32(wgA); DECL32(wgB); DECL32(wgC); DECL32(wgD);
        LOAD32(Whh0, lane,        wgA);
        LOAD32(Whh0, 64 + lane,   wgB);
        LOAD32(Whh0, 128 + lane,  wgC);
        LOAD32(Whh0, 192 + lane,  wgD);
        const float b0 = bih0[lane]       + bhh0[lane];
        const float b1 = bih0[64 + lane]  + bhh0[64 + lane];
        const float b2 = bih0[128 + lane] + bhh0[128 + lane];
        const float b3 = bih0[192 + lane] + bhh0[192 + lane];
        const float wx0 = Wih0[lane];       const float wx1 = Wih0[64 + lane];
        const float wx2 = Wih0[128 + lane]; const float wx3 = Wih0[192 + lane];
        float cst = c0in[b * HD + lane];
        h0ring[NS - 1][lane] = (_Float16)h0in[b * HD + lane];
        const float* xrow = x + (size_t)b * T;
        __syncthreads();

        for (int p = 0; p < nphase; ++p) {
            const int t0 = p * KP;
            if (t0 < T) {
                #pragma unroll 1
                for (int k = 0; k < KP; ++k) {
                    const int t = t0 + k;
                    if (t >= T) break;
                    const float xv = xrow[t];                   // uniform scalar load
                    const h8* hp = (const h8*)h0ring[(t + NS - 1) & (NS - 1)];
                    float a00 = b0, a01 = 0.f, a10 = b1, a11 = 0.f;
                    float a20 = b2, a21 = 0.f, a30 = b3, a31 = 0.f;
                    DOT4N(hp);
                    const float ai = fmaf(wx0, xv, a00 + a01);
                    const float af = fmaf(wx1, xv, a10 + a11);
                    const float ag = fmaf(wx2, xv, a20 + a21);
                    const float ao = fmaf(wx3, xv, a30 + a31);
                    const float iv = fsig(ai), fv = fsig(af);
                    const float gv = ftanh_fast(ag), ov = fsig(ao);
                    cst = fmaf(fv, cst, iv * gv);
                    const float h = ov * ftanh_fast(cst);
                    h0ring[t & (NS - 1)][lane] = (_Float16)h;   // same-wave roundtrip
                }
            }
            __syncthreads();
        }
    } else if (wave == 1) {
        // ================= C: layer-1 recurrence (lag 2 phases) =================
        DECL32(wgA); DECL32(wgB); DECL32(wgC); DECL32(wgD);
        LOAD32(Whh1, lane,        wgA);
        LOAD32(Whh1, 64 + lane,   wgB);
        LOAD32(Whh1, 128 + lane,  wgC);
        LOAD32(Whh1, 192 + lane,  wgD);
        float cst = c0in[B * HD + b * HD + lane];
        h1ring[NS - 1][lane] = (_Float16)h0in[B * HD + b * HD + lane];
        __syncthreads();

        for (int p = 0; p < nphase; ++p) {
            const int t0 = (p - 2) * KP;
            if (p >= 2 && t0 < T) {
                #pragma unroll 1
                for (int k = 0; k < KP; ++k) {
                    const int t = t0 + k;
                    if (t >= T) break;
                    const int s = t & (NS - 1);
                    const float x0 = xpring[s][0][lane];        // issued early,
                    const float x1 = xpring[s][1][lane];        // consumed after dots
                    const float x2 = xpring[s][2][lane];
                    const float x3 = xpring[s][3][lane];
                    const h8* hp = (const h8*)h1ring[(t + NS - 1) & (NS - 1)];
                    float a00 = 0.f, a01 = 0.f, a10 = 0.f, a11 = 0.f;
                    float a20 = 0.f, a21 = 0.f, a30 = 0.f, a31 = 0.f;
                    DOT4N(hp);
                    const float ai = x0 + a00 + a01;
                    const float af = x1 + a10 + a11;
                    const float ag = x2 + a20 + a21;
                    const float ao = x3 + a30 + a31;
                    const float iv = fsig(ai), fv = fsig(af);
                    const float gv = ftanh_fast(ag), ov = fsig(ao);
                    cst = fmaf(fv, cst, iv * gv);
                    const float h = ov * ftanh_fast(cst);
                    h1ring[s][lane] = (_Float16)h;
                    h1f32[s][lane]  = h;                        // f32 h for output head
                }
            }
            __syncthreads();
        }
    } else if (wave <= 3) {
        // ================= B0/B1: layer-1 input projection (lag 1 phase) =========
        DECL32(wgA); DECL32(wgB);
        const int g0 = (wave - 2) * 2;
        LOAD32(Wih1, g0 * HD + lane,       wgA);
        LOAD32(Wih1, (g0 + 1) * HD + lane, wgB);
        const float b0 = bih1[g0 * HD + lane]       + bhh1[g0 * HD + lane];
        const float b1 = bih1[(g0 + 1) * HD + lane] + bhh1[(g0 + 1) * HD + lane];
        __syncthreads();

        for (int p = 0; p < nphase; ++p) {
            const int t0 = (p - 1) * KP;
            if (p >= 1 && t0 < T) {
                #pragma unroll 1
                for (int k = 0; k < KP; ++k) {
                    const int t = t0 + k;
                    if (t >= T) break;
                    const int s = t & (NS - 1);
                    const h8* hp = (const h8*)h0ring[s];
                    float a00 = b0, a01 = 0.f, a10 = b1, a11 = 0.f;
                    DOT2N(hp);
                    xpring[s][g0][lane]     = a00 + a01;
                    xpring[s][g0 + 1][lane] = a10 + a11;
                }
            }
            __syncthreads();
        }
    } else {
        // ================= D: output head (lag 3 phases) =================
        const float blin0 = blin[0];
        __syncthreads();

        for (int p = 0; p < nphase; ++p) {
            const int t0 = (p - 3) * KP;
            if (p >= 3 && t0 < T && lane < KP) {
                const int t = t0 + lane;
                if (t < T) {
                    const float4* hv4 = (const float4*)h1f32[t & (NS - 1)];
                    const float4* wp  = (const float4*)Wlin;
                    float acc = blin0;
                    #pragma unroll
                    for (int q = 0; q < 16; ++q) {
                        const float4 hv = hv4[q];
                        const float4 wv = wp[q];
                        acc = fmaf(wv.x, hv.x, acc);
                        acc = fmaf(wv.y, hv.y, acc);
                        acc = fmaf(wv.z, hv.z, acc);
                        acc = fmaf(wv.w, hv.w, acc);
                    }
                    out[(size_t)b * T + t] = acc;
                }
            }
            __syncthreads();
        }
    }
}

extern "C" void kernel_launch(void* const* d_in, const int* in_sizes, int n_in,
                              void* d_out, int out_size, void* d_ws, size_t ws_size,
                              hipStream_t stream)
{
    const float* x    = (const float*)d_in[0];
    const float* h0   = (const float*)d_in[1];
    const float* c0   = (const float*)d_in[2];
    const float* Wih0 = (const float*)d_in[3];
    const float* Whh0 = (const float*)d_in[4];
    const float* bih0 = (const float*)d_in[5];
    const float* bhh0 = (const float*)d_in[6];
    const float* Wih1 = (const float*)d_in[7];
    const float* Whh1 = (const float*)d_in[8];
    const float* bih1 = (const float*)d_in[9];
    const float* bhh1 = (const float*)d_in[10];
    const float* Wlin = (const float*)d_in[11];
    const float* blin = (const float*)d_in[12];
    float* out = (float*)d_out;

    const int B = in_sizes[1] / (2 * HD);   // h0 is [2,B,HD]
    const int T = in_sizes[0] / B;          // input is [B,T]

    lstm2_kernel<<<dim3(B), dim3(320), 0, stream>>>(
        x, h0, c0, Wih0, Whh0, bih0, bhh0,
        Wih1, Whh1, bih1, bhh1, Wlin, blin, out, B, T);
}